// Round 2
// baseline (658.788 us; speedup 1.0000x reference)
//
#include <hip/hip_runtime.h>

#define N_GRAPHS 1024
#define N_FEAT 128   // = 32 float4

// ---------------------------------------------------------------------------
// Kernel 1: segment boundaries from the SORTED batch array (int32 on device —
// the harness converts all integer inputs to int32).
// start[g] = first index i with batch[i] >= g ; start[N_GRAPHS] = n.
// Each entry is written exactly once (union of (batch[i-1], batch[i]] ranges
// plus the tail covers all g in [0, N_GRAPHS]), so no zero-init needed.
// ---------------------------------------------------------------------------
__global__ void boundary_kernel(const int* __restrict__ batch, int n,
                                int* __restrict__ start) {
    int i = blockIdx.x * blockDim.x + threadIdx.x;
    if (i >= n) return;
    int cur  = batch[i];
    int prev = (i == 0) ? -1 : batch[i - 1];
    for (int g = prev + 1; g <= cur; ++g) start[g] = i;
    if (i == n - 1) {
        for (int g = cur + 1; g <= N_GRAPHS; ++g) start[g] = n;
    }
}

// ---------------------------------------------------------------------------
// Kernel 2: one block per graph. 256 threads = 8 row-groups x 32 float4 cols.
// Each iteration reads 8 complete rows (4 KB) fully coalesced, 4x unrolled
// (rows r, r+8, r+16, r+24) for 4 loads in flight per thread.
// Then the block writes scores[s..e) = 1/count (uniform, coalesced).
// ---------------------------------------------------------------------------
__global__ __launch_bounds__(256) void pool_kernel(
        const float* __restrict__ x,
        const int* __restrict__ start,
        float* __restrict__ pooled,    // [N_GRAPHS * N_FEAT]
        float* __restrict__ scores) {  // [n]
    const int g = blockIdx.x;
    const int s = start[g];
    const int e = start[g + 1];
    const int n = e - s;
    const float inv = 1.0f / (float)max(n, 1);

    const int tid = threadIdx.x;
    const int col = tid & 31;   // float4 column 0..31
    const int rg  = tid >> 5;   // row group 0..7

    const float4* xp = (const float4*)x + (size_t)s * 32;

    float4 a0 = {0.f, 0.f, 0.f, 0.f};
    float4 a1 = {0.f, 0.f, 0.f, 0.f};
    float4 a2 = {0.f, 0.f, 0.f, 0.f};
    float4 a3 = {0.f, 0.f, 0.f, 0.f};

    int r = rg;
    for (; r + 24 < n; r += 32) {
        float4 v0 = xp[(size_t)(r     ) * 32 + col];
        float4 v1 = xp[(size_t)(r +  8) * 32 + col];
        float4 v2 = xp[(size_t)(r + 16) * 32 + col];
        float4 v3 = xp[(size_t)(r + 24) * 32 + col];
        a0.x += v0.x; a0.y += v0.y; a0.z += v0.z; a0.w += v0.w;
        a1.x += v1.x; a1.y += v1.y; a1.z += v1.z; a1.w += v1.w;
        a2.x += v2.x; a2.y += v2.y; a2.z += v2.z; a2.w += v2.w;
        a3.x += v3.x; a3.y += v3.y; a3.z += v3.z; a3.w += v3.w;
    }
    for (; r < n; r += 8) {
        float4 v = xp[(size_t)r * 32 + col];
        a0.x += v.x; a0.y += v.y; a0.z += v.z; a0.w += v.w;
    }
    a0.x += a1.x + a2.x + a3.x;
    a0.y += a1.y + a2.y + a3.y;
    a0.z += a1.z + a2.z + a3.z;
    a0.w += a1.w + a2.w + a3.w;

    __shared__ float4 red[256];
    red[tid] = a0;
    __syncthreads();

    if (tid < 32) {
        float4 sum = red[tid];
        #pragma unroll
        for (int k = 1; k < 8; ++k) {
            float4 v = red[k * 32 + tid];
            sum.x += v.x; sum.y += v.y; sum.z += v.z; sum.w += v.w;
        }
        float4 outv;
        outv.x = sum.x * inv;
        outv.y = sum.y * inv;
        outv.z = sum.z * inv;
        outv.w = sum.w * inv;
        ((float4*)pooled)[g * 32 + tid] = outv;
    }

    // attention_scores for this graph's nodes: uniform value, coalesced writes
    for (int i = s + tid; i < e; i += 256) {
        scores[i] = inv;
    }
}

extern "C" void kernel_launch(void* const* d_in, const int* in_sizes, int n_in,
                              void* d_out, int out_size, void* d_ws, size_t ws_size,
                              hipStream_t stream) {
    const float* x     = (const float*)d_in[0];
    // d_in[1] = edge_index: unused by the reference -> never read (saves traffic)
    const int*   batch = (const int*)d_in[2];   // harness stores integers as int32

    float* out    = (float*)d_out;
    float* pooled = out;                               // [1024*128]
    float* scores = out + (size_t)N_GRAPHS * N_FEAT;   // [n]

    int* start = (int*)d_ws;                           // [N_GRAPHS + 1]

    const int n = in_sizes[2];                         // 1,000,000 nodes

    boundary_kernel<<<(n + 255) / 256, 256, 0, stream>>>(batch, n, start);
    pool_kernel<<<N_GRAPHS, 256, 0, stream>>>(x, start, pooled, scores);
}